// Round 10
// baseline (79.062 us; speedup 1.0000x reference)
//
#include <hip/hip_runtime.h>
#include <math.h>

#define VOCAB   128000
#define VOCAB4  32000            // float4 per row
#define NROW    256
#define TOPC    63
#define HPR     2                // stream blocks per row
#define BS      1024
#define H4      (VOCAB4 / HPR)   // 16000 float4 per half
#define FIT     15
#define TAILT   (H4 - FIT * BS)  // 640
#define LCAP    320              // per-block LDS cap (E~190, sd~14)
#define CAP     512              // per-row global cap (E~381, sd~20)
#define T0      11.0f            // collect threshold; top-63 cutoff ~13.2
#define BSM     512              // merge block size (1 candidate per thread)

typedef float f32x4 __attribute__((ext_vector_type(4)));

// ws: [0) u32 cnt[NROW] | [1024) f32 psum[NROW*HPR] | [4096) f32 cval[NROW*CAP]
//     | [4096+512KB) i32 cidx[NROW*CAP]

__device__ __forceinline__ unsigned ordf(float v) {
  unsigned u = __float_as_uint(v);
  return (u & 0x80000000u) ? ~u : (u | 0x80000000u);   // order-preserving f32->u32
}

__device__ __forceinline__ void proc4(
    float4 x, int j4, float inv_t, float4* __restrict__ o4,
    float& s0, float& s1, float& s2, float& s3,
    unsigned int* nc, float* cv, int* ci)
{
  float vx = x.x*inv_t, vy = x.y*inv_t, vz = x.z*inv_t, vw = x.w*inv_t;
  f32x4 v = {vx, vy, vz, vw};
  *(f32x4*)&o4[j4] = v;
  s0 += __expf(vx); s1 += __expf(vy); s2 += __expf(vz); s3 += __expf(vw);
  // rare branch (p~0.003/elem)
  if (x.x > T0) { unsigned q = atomicAdd(nc,1u); if (q<LCAP){cv[q]=vx; ci[q]=4*j4+0;} }
  if (x.y > T0) { unsigned q = atomicAdd(nc,1u); if (q<LCAP){cv[q]=vy; ci[q]=4*j4+1;} }
  if (x.z > T0) { unsigned q = atomicAdd(nc,1u); if (q<LCAP){cv[q]=vz; ci[q]=4*j4+2;} }
  if (x.w > T0) { unsigned q = atomicAdd(nc,1u); if (q<LCAP){cv[q]=vw; ci[q]=4*j4+3;} }
}

#define SGB_READS(N) __builtin_amdgcn_sched_group_barrier(0x20u, (N), 0)

__global__ __launch_bounds__(BS, 8) void stream_kernel(
    const float* __restrict__ logits, const float* __restrict__ temps,
    float* __restrict__ out, unsigned int* __restrict__ cnt,
    float* __restrict__ psum, float* __restrict__ cval, int* __restrict__ cidx)
{
  const int blk = blockIdx.x;
  const int row = blk >> 1;
  const int hh  = blk & 1;
  const int tid = threadIdx.x;

  __shared__ float lcv[LCAP]; __shared__ int lci[LCAP];
  __shared__ float wsum[BS / 64];
  __shared__ unsigned int nc_sh, base_sh;

  if (tid == 0) nc_sh = 0u;
  __syncthreads();

  const float temp  = temps[row];
  const float inv_t = 1.0f / ((temp == 0.0f) ? 1.0f : temp);

  const float4* __restrict__ lg4 =
      reinterpret_cast<const float4*>(logits + (size_t)row * VOCAB);
  float4* __restrict__ o4 =
      reinterpret_cast<float4*>(out + NROW + (size_t)row * VOCAB);

  float s0 = 0.f, s1 = 0.f, s2 = 0.f, s3 = 0.f;

  // ---- software-pipelined stream: 4-deep prefetch, straight-line ----
  const int b = hh * H4 + tid;

  float4 c0 = lg4[b+ 0*BS], c1 = lg4[b+ 1*BS], c2 = lg4[b+ 2*BS], c3 = lg4[b+ 3*BS];

  // group A: prefetch iters 4..7, process 0..3
  float4 n0 = lg4[b+ 4*BS], n1 = lg4[b+ 5*BS], n2 = lg4[b+ 6*BS], n3 = lg4[b+ 7*BS];
  SGB_READS(4);
  proc4(c0, b+ 0*BS, inv_t, o4, s0,s1,s2,s3, &nc_sh, lcv, lci);
  proc4(c1, b+ 1*BS, inv_t, o4, s0,s1,s2,s3, &nc_sh, lcv, lci);
  proc4(c2, b+ 2*BS, inv_t, o4, s0,s1,s2,s3, &nc_sh, lcv, lci);
  proc4(c3, b+ 3*BS, inv_t, o4, s0,s1,s2,s3, &nc_sh, lcv, lci);

  // group B: prefetch iters 8..11, process 4..7
  c0 = lg4[b+ 8*BS]; c1 = lg4[b+ 9*BS]; c2 = lg4[b+10*BS]; c3 = lg4[b+11*BS];
  SGB_READS(4);
  proc4(n0, b+ 4*BS, inv_t, o4, s0,s1,s2,s3, &nc_sh, lcv, lci);
  proc4(n1, b+ 5*BS, inv_t, o4, s0,s1,s2,s3, &nc_sh, lcv, lci);
  proc4(n2, b+ 6*BS, inv_t, o4, s0,s1,s2,s3, &nc_sh, lcv, lci);
  proc4(n3, b+ 7*BS, inv_t, o4, s0,s1,s2,s3, &nc_sh, lcv, lci);

  // group C: prefetch iters 12..14, process 8..11
  n0 = lg4[b+12*BS]; n1 = lg4[b+13*BS]; n2 = lg4[b+14*BS];
  SGB_READS(3);
  proc4(c0, b+ 8*BS, inv_t, o4, s0,s1,s2,s3, &nc_sh, lcv, lci);
  proc4(c1, b+ 9*BS, inv_t, o4, s0,s1,s2,s3, &nc_sh, lcv, lci);
  proc4(c2, b+10*BS, inv_t, o4, s0,s1,s2,s3, &nc_sh, lcv, lci);
  proc4(c3, b+11*BS, inv_t, o4, s0,s1,s2,s3, &nc_sh, lcv, lci);

  // group D: process 12..14 (loads already in flight from C)
  proc4(n0, b+12*BS, inv_t, o4, s0,s1,s2,s3, &nc_sh, lcv, lci);
  proc4(n1, b+13*BS, inv_t, o4, s0,s1,s2,s3, &nc_sh, lcv, lci);
  proc4(n2, b+14*BS, inv_t, o4, s0,s1,s2,s3, &nc_sh, lcv, lci);

  // E: tail 640 float4 (one dependent round-trip; negligible)
  if (tid < TAILT) {
    const int jt = hh * H4 + FIT * BS + tid;
    float4 t = lg4[jt];
    proc4(t, jt, inv_t, o4, s0,s1,s2,s3, &nc_sh, lcv, lci);
  }

  // ---- block sum-exp reduce -> psum (fixed order, deterministic) ----
  float s = (s0 + s1) + (s2 + s3);
  #pragma unroll
  for (int off = 32; off > 0; off >>= 1) s += __shfl_down(s, off);
  if ((tid & 63) == 0) wsum[tid >> 6] = s;
  __syncthreads();
  if (tid == 0) {
    float t = 0.f;
    #pragma unroll
    for (int w = 0; w < BS / 64; ++w) t += wsum[w];
    psum[row * HPR + hh] = t;
    unsigned nloc = (nc_sh < (unsigned)LCAP) ? nc_sh : (unsigned)LCAP;
    // overflow -> force merge's rescan ladder (total > CAP guaranteed)
    unsigned add = nloc + ((nc_sh > (unsigned)LCAP) ? 2048u : 0u);
    base_sh = atomicAdd(&cnt[row], add);
  }
  __syncthreads();

  // ---- coalesced flush of LDS candidates to per-row global list ----
  const int nloc = ((int)nc_sh < LCAP) ? (int)nc_sh : LCAP;
  const unsigned base = base_sh;
  for (int i = tid; i < nloc; i += BS) {
    unsigned p = base + i;
    if (p < CAP) { cval[row * CAP + p] = lcv[i]; cidx[row * CAP + p] = lci[i]; }
  }
  // no fence: the kernel boundary is the coherence point
}

__global__ __launch_bounds__(BSM) void merge_kernel(
    const float* __restrict__ logits, const float* __restrict__ temps,
    const float* __restrict__ topps, const float* __restrict__ topks,
    const float* __restrict__ noise, float* __restrict__ out,
    const unsigned int* __restrict__ cnt, const float* __restrict__ psum,
    const float* __restrict__ cval, const int* __restrict__ cidx)
{
  const int row = blockIdx.x;
  const int tid = threadIdx.x;

  __shared__ float cv2[CAP]; __shared__ int ci2[CAP];
  __shared__ unsigned long long kv[CAP];
  __shared__ float sv[64];   __shared__ int si[64];
  __shared__ float sp_s[64], sc_s[64], noi_s[64];
  __shared__ unsigned int nc2;

  if (tid < 64) noi_s[tid] = noise[(size_t)row * VOCAB + tid];

  const float temp  = temps[row];
  const float inv_t = 1.0f / ((temp == 0.0f) ? 1.0f : temp);
  const float S = psum[row * HPR + 0] + psum[row * HPR + 1];  // fixed order

  int total = (int)cnt[row];
  int n = (total < CAP) ? total : CAP;
  for (int i = tid; i < n; i += BSM) {
    cv2[i] = cval[row * CAP + i];
    ci2[i] = cidx[row * CAP + i];
  }
  __syncthreads();

  // robustness ladder (dead for bench data): rescan full L3-warm row
  float thr = T0;
  for (int att = 0; att < 4 && (total < TOPC || total > CAP); ++att) {
    thr = (total > CAP) ? (thr + 2.0f) : (thr - 4.0f);
    __syncthreads();
    if (tid == 0) nc2 = 0u;
    __syncthreads();
    const float* __restrict__ lg = logits + (size_t)row * VOCAB;
    for (int k = tid; k < VOCAB; k += BSM) {
      float x = lg[k];
      if (x > thr) {
        unsigned p = atomicAdd(&nc2, 1u);
        if (p < CAP) { cv2[p] = x * inv_t; ci2[p] = k; }
      }
    }
    __syncthreads();
    total = (int)nc2;
    n = (total < CAP) ? total : CAP;
  }

  // ---- packed sort keys: ascending u64 == (value desc, index asc) ----
  if (tid < n)
    kv[tid] = ((unsigned long long)(~ordf(cv2[tid])) << 32) | (unsigned)ci2[tid];
  __syncthreads();

  // ---- rank select: one candidate per thread, batched LDS reads ----
  if (tid < n) {
    const unsigned long long me = kv[tid];
    int r = 0;
    #pragma unroll 8
    for (int k = 0; k < n; ++k) r += (int)(kv[k] < me);
    if (r < 64) { sv[r] = cv2[tid]; si[r] = ci2[tid]; }
  }
  __syncthreads();

  const int lim = (n < TOPC) ? n : TOPC;

  // parallel per-slot prob + gumbel score
  if (tid < lim) {
    float sp = __expf(sv[tid]) * (1.0f / S);
    sp_s[tid] = sp;
    float u = noi_s[tid];
    sc_s[tid] = logf(sp) + (-logf(-logf(u)));
  }
  __syncthreads();

  // serial 63-step joint-mask scan + argmax
  if (tid == 0) {
    const float kk = topks[row];
    const float tp = topps[row];
    float cdf = 0.f, best = -INFINITY; int bestj = 0;
    for (int k = 0; k < lim; ++k) {
      if (((float)k < kk) && (cdf <= tp)) {
        float sc = sc_s[k];
        if (sc > best) { best = sc; bestj = k; }
      }
      cdf += sp_s[k];                      // exclusive cumsum semantics
    }
    int token = (n > 0) ? si[bestj] : 0;
    if (temp == 0.0f && n > 0) token = si[0];
    out[row] = (float)token;
  }
}

extern "C" void kernel_launch(void* const* d_in, const int* in_sizes, int n_in,
                              void* d_out, int out_size, void* d_ws, size_t ws_size,
                              hipStream_t stream) {
  const float* logits = (const float*)d_in[0];
  const float* temps  = (const float*)d_in[1];
  const float* topps  = (const float*)d_in[2];
  const float* topks  = (const float*)d_in[3];
  const float* noise  = (const float*)d_in[4];
  float* out = (float*)d_out;

  char* ws = (char*)d_ws;
  unsigned int* cnt = (unsigned int*)(ws);
  float* psum = (float*)(ws + 1024);
  float* cval = (float*)(ws + 4096);
  int*   cidx = (int*)  (ws + 4096 + (size_t)NROW * CAP * 4);

  hipMemsetAsync(cnt, 0, 1024, stream);
  stream_kernel<<<NROW * HPR, BS, 0, stream>>>(logits, temps, out, cnt, psum, cval, cidx);
  merge_kernel<<<NROW, BSM, 0, stream>>>(logits, temps, topps, topks, noise, out,
                                         cnt, psum, cval, cidx);
}

// Round 11
// 78.153 us; speedup vs baseline: 1.0116x; 1.0116x over previous
//
#include <hip/hip_runtime.h>
#include <math.h>

#define VOCAB   128000
#define VOCAB4  32000            // float4 per row
#define NROW    256
#define TOPC    63
#define HPR     2                // stream blocks per row
#define BS      1024
#define H4      (VOCAB4 / HPR)   // 16000 float4 per half
#define FIT     15
#define TAILT   (H4 - FIT * BS)  // 640
#define LCAP    320              // per-block LDS cap (E~190, sd~14)
#define CAP     512              // per-row global cap (E~381, sd~20)
#define T0      11.0f            // collect threshold; top-63 cutoff ~13.2
#define BSM     512              // merge block size (1 candidate per thread)

typedef float f32x4 __attribute__((ext_vector_type(4)));

// ws: [0) u32 cnt[NROW] | [1024) f32 psum[NROW*HPR] | [4096) f32 cval[NROW*CAP]
//     | [4096+512KB) i32 cidx[NROW*CAP]

__device__ __forceinline__ unsigned ordf(float v) {
  unsigned u = __float_as_uint(v);
  return (u & 0x80000000u) ? ~u : (u | 0x80000000u);   // order-preserving f32->u32
}

// ---- explicit-VMEM macros: compiler cannot reorder volatile asm vs asm ----
#define GLD(dst, ptr) \
  asm volatile("global_load_dwordx4 %0, %1, off" : "=v"(dst) : "v"(ptr) : "memory")
#define GST(ptr, val) \
  asm volatile("global_store_dwordx4 %0, %1, off" :: "v"(ptr), "v"(val) : "memory")
// tied "+v": any use of dst must follow the wait (defeats use-hoisting, rule #18)
#define WAITN_(dst, n) \
  asm volatile("s_waitcnt vmcnt(" #n ")" : "+v"(dst) :: "memory")
#define WAITN(dst, n) WAITN_(dst, n)

__device__ __forceinline__ void procp(
    f32x4 x, int j4, float inv_t, float* __restrict__ outp,
    float& s0, float& s1, float& s2, float& s3,
    unsigned int* nc, float* cv, int* ci)
{
  f32x4 v;
  v.x = x.x*inv_t; v.y = x.y*inv_t; v.z = x.z*inv_t; v.w = x.w*inv_t;
  GST(outp + 4*(size_t)j4, v);            // store is asm: vmcnt ledger stays exact
  s0 += __expf(v.x); s1 += __expf(v.y); s2 += __expf(v.z); s3 += __expf(v.w);
  // rare branch (p~0.003/elem); LDS atomic = lgkmcnt, does not touch vmcnt
  if (x.x > T0) { unsigned q = atomicAdd(nc,1u); if (q<LCAP){cv[q]=v.x; ci[q]=4*j4+0;} }
  if (x.y > T0) { unsigned q = atomicAdd(nc,1u); if (q<LCAP){cv[q]=v.y; ci[q]=4*j4+1;} }
  if (x.z > T0) { unsigned q = atomicAdd(nc,1u); if (q<LCAP){cv[q]=v.z; ci[q]=4*j4+2;} }
  if (x.w > T0) { unsigned q = atomicAdd(nc,1u); if (q<LCAP){cv[q]=v.w; ci[q]=4*j4+3;} }
}

__global__ __launch_bounds__(BS, 8) void stream_kernel(
    const float* __restrict__ logits, const float* __restrict__ temps,
    float* __restrict__ out, unsigned int* __restrict__ cnt,
    float* __restrict__ psum, float* __restrict__ cval, int* __restrict__ cidx)
{
  const int blk = blockIdx.x;
  const int row = blk >> 1;
  const int hh  = blk & 1;
  const int tid = threadIdx.x;

  __shared__ float lcv[LCAP]; __shared__ int lci[LCAP];
  __shared__ float wsum[BS / 64];
  __shared__ unsigned int nc_sh, base_sh;

  if (tid == 0) nc_sh = 0u;
  __syncthreads();

  const float temp  = temps[row];
  const float inv_t = 1.0f / ((temp == 0.0f) ? 1.0f : temp);

  const float4* __restrict__ lg4 =
      reinterpret_cast<const float4*>(logits + (size_t)row * VOCAB);
  float* __restrict__ outp = out + NROW + (size_t)row * VOCAB;

  float s0 = 0.f, s1 = 0.f, s2 = 0.f, s3 = 0.f;
  const int b = hh * H4 + tid;

  // ---- 8-deep asm pipeline: L0..L7 upfront, then wait/process/store/refill ----
  f32x4 c0,c1,c2,c3,c4,c5,c6,c7;
  GLD(c0, lg4 + b + 0*BS); GLD(c1, lg4 + b + 1*BS);
  GLD(c2, lg4 + b + 2*BS); GLD(c3, lg4 + b + 3*BS);
  GLD(c4, lg4 + b + 4*BS); GLD(c5, lg4 + b + 5*BS);
  GLD(c6, lg4 + b + 6*BS); GLD(c7, lg4 + b + 7*BS);

#define PSTEP(C, IDX, N) \
  WAITN(C, N); \
  procp(C, b + (IDX)*BS, inv_t, outp, s0,s1,s2,s3, &nc_sh, lcv, lci)

  // vmcnt = ops issued after L_i (loads+stores retire in issue order)
  PSTEP(c0, 0,  7);  GLD(c0, lg4 + b +  8*BS);
  PSTEP(c1, 1,  8);  GLD(c1, lg4 + b +  9*BS);
  PSTEP(c2, 2,  9);  GLD(c2, lg4 + b + 10*BS);
  PSTEP(c3, 3, 10);  GLD(c3, lg4 + b + 11*BS);
  PSTEP(c4, 4, 11);  GLD(c4, lg4 + b + 12*BS);
  PSTEP(c5, 5, 12);  GLD(c5, lg4 + b + 13*BS);
  PSTEP(c6, 6, 13);  GLD(c6, lg4 + b + 14*BS);
  PSTEP(c7, 7, 14);
  PSTEP(c0, 8, 13);
  PSTEP(c1, 9, 12);
  PSTEP(c2,10, 11);
  PSTEP(c3,11, 10);
  PSTEP(c4,12,  9);
  PSTEP(c5,13,  8);
  PSTEP(c6,14,  7);
#undef PSTEP

  // ---- tail 640 float4 (plain code; its waitcnt accounting stays valid) ----
  if (tid < TAILT) {
    const int jt = b + FIT * BS;
    float4 t = lg4[jt];
    f32x4 x; x.x = t.x; x.y = t.y; x.z = t.z; x.w = t.w;
    f32x4 v;
    v.x = x.x*inv_t; v.y = x.y*inv_t; v.z = x.z*inv_t; v.w = x.w*inv_t;
    *(f32x4*)(outp + 4*(size_t)jt) = v;
    s0 += __expf(v.x); s1 += __expf(v.y); s2 += __expf(v.z); s3 += __expf(v.w);
    if (x.x > T0) { unsigned q = atomicAdd(&nc_sh,1u); if (q<LCAP){lcv[q]=v.x; lci[q]=4*jt+0;} }
    if (x.y > T0) { unsigned q = atomicAdd(&nc_sh,1u); if (q<LCAP){lcv[q]=v.y; lci[q]=4*jt+1;} }
    if (x.z > T0) { unsigned q = atomicAdd(&nc_sh,1u); if (q<LCAP){lcv[q]=v.z; lci[q]=4*jt+2;} }
    if (x.w > T0) { unsigned q = atomicAdd(&nc_sh,1u); if (q<LCAP){lcv[q]=v.w; lci[q]=4*jt+3;} }
  }

  // ---- block sum-exp reduce -> psum (fixed order, deterministic) ----
  float s = (s0 + s1) + (s2 + s3);
  #pragma unroll
  for (int off = 32; off > 0; off >>= 1) s += __shfl_down(s, off);
  if ((tid & 63) == 0) wsum[tid >> 6] = s;
  __syncthreads();
  if (tid == 0) {
    float t = 0.f;
    #pragma unroll
    for (int w = 0; w < BS / 64; ++w) t += wsum[w];
    psum[row * HPR + hh] = t;
    unsigned nloc = (nc_sh < (unsigned)LCAP) ? nc_sh : (unsigned)LCAP;
    // overflow -> force merge's rescan ladder (total > CAP guaranteed)
    unsigned add = nloc + ((nc_sh > (unsigned)LCAP) ? 2048u : 0u);
    base_sh = atomicAdd(&cnt[row], add);
  }
  __syncthreads();

  // ---- coalesced flush of LDS candidates to per-row global list ----
  const int nloc = ((int)nc_sh < LCAP) ? (int)nc_sh : LCAP;
  const unsigned base = base_sh;
  for (int i = tid; i < nloc; i += BS) {
    unsigned p = base + i;
    if (p < CAP) { cval[row * CAP + p] = lcv[i]; cidx[row * CAP + p] = lci[i]; }
  }
  // no fence: the kernel boundary is the coherence point
}

__global__ __launch_bounds__(BSM) void merge_kernel(
    const float* __restrict__ logits, const float* __restrict__ temps,
    const float* __restrict__ topps, const float* __restrict__ topks,
    const float* __restrict__ noise, float* __restrict__ out,
    const unsigned int* __restrict__ cnt, const float* __restrict__ psum,
    const float* __restrict__ cval, const int* __restrict__ cidx)
{
  const int row = blockIdx.x;
  const int tid = threadIdx.x;

  __shared__ float cv2[CAP]; __shared__ int ci2[CAP];
  __shared__ unsigned long long kv[CAP];
  __shared__ float sv[64];   __shared__ int si[64];
  __shared__ float sp_s[64], sc_s[64], noi_s[64];
  __shared__ unsigned int nc2;

  if (tid < 64) noi_s[tid] = noise[(size_t)row * VOCAB + tid];

  const float temp  = temps[row];
  const float inv_t = 1.0f / ((temp == 0.0f) ? 1.0f : temp);
  const float S = psum[row * HPR + 0] + psum[row * HPR + 1];  // fixed order

  int total = (int)cnt[row];
  int n = (total < CAP) ? total : CAP;
  for (int i = tid; i < n; i += BSM) {
    cv2[i] = cval[row * CAP + i];
    ci2[i] = cidx[row * CAP + i];
  }
  __syncthreads();

  // robustness ladder (dead for bench data): rescan full L3-warm row
  float thr = T0;
  for (int att = 0; att < 4 && (total < TOPC || total > CAP); ++att) {
    thr = (total > CAP) ? (thr + 2.0f) : (thr - 4.0f);
    __syncthreads();
    if (tid == 0) nc2 = 0u;
    __syncthreads();
    const float* __restrict__ lg = logits + (size_t)row * VOCAB;
    for (int k = tid; k < VOCAB; k += BSM) {
      float x = lg[k];
      if (x > thr) {
        unsigned p = atomicAdd(&nc2, 1u);
        if (p < CAP) { cv2[p] = x * inv_t; ci2[p] = k; }
      }
    }
    __syncthreads();
    total = (int)nc2;
    n = (total < CAP) ? total : CAP;
  }

  // ---- packed sort keys: ascending u64 == (value desc, index asc) ----
  if (tid < n)
    kv[tid] = ((unsigned long long)(~ordf(cv2[tid])) << 32) | (unsigned)ci2[tid];
  __syncthreads();

  // ---- rank select: one candidate per thread, batched LDS reads ----
  if (tid < n) {
    const unsigned long long me = kv[tid];
    int r = 0;
    #pragma unroll 8
    for (int k = 0; k < n; ++k) r += (int)(kv[k] < me);
    if (r < 64) { sv[r] = cv2[tid]; si[r] = ci2[tid]; }
  }
  __syncthreads();

  const int lim = (n < TOPC) ? n : TOPC;

  // parallel per-slot prob + gumbel score
  if (tid < lim) {
    float sp = __expf(sv[tid]) * (1.0f / S);
    sp_s[tid] = sp;
    float u = noi_s[tid];
    sc_s[tid] = logf(sp) + (-logf(-logf(u)));
  }
  __syncthreads();

  // serial 63-step joint-mask scan + argmax
  if (tid == 0) {
    const float kk = topks[row];
    const float tp = topps[row];
    float cdf = 0.f, best = -INFINITY; int bestj = 0;
    for (int k = 0; k < lim; ++k) {
      if (((float)k < kk) && (cdf <= tp)) {
        float sc = sc_s[k];
        if (sc > best) { best = sc; bestj = k; }
      }
      cdf += sp_s[k];                      // exclusive cumsum semantics
    }
    int token = (n > 0) ? si[bestj] : 0;
    if (temp == 0.0f && n > 0) token = si[0];
    out[row] = (float)token;
  }
}

extern "C" void kernel_launch(void* const* d_in, const int* in_sizes, int n_in,
                              void* d_out, int out_size, void* d_ws, size_t ws_size,
                              hipStream_t stream) {
  const float* logits = (const float*)d_in[0];
  const float* temps  = (const float*)d_in[1];
  const float* topps  = (const float*)d_in[2];
  const float* topks  = (const float*)d_in[3];
  const float* noise  = (const float*)d_in[4];
  float* out = (float*)d_out;

  char* ws = (char*)d_ws;
  unsigned int* cnt = (unsigned int*)(ws);
  float* psum = (float*)(ws + 1024);
  float* cval = (float*)(ws + 4096);
  int*   cidx = (int*)  (ws + 4096 + (size_t)NROW * CAP * 4);

  hipMemsetAsync(cnt, 0, 1024, stream);
  stream_kernel<<<NROW * HPR, BS, 0, stream>>>(logits, temps, out, cnt, psum, cval, cidx);
  merge_kernel<<<NROW, BSM, 0, stream>>>(logits, temps, topps, topks, noise, out,
                                         cnt, psum, cval, cidx);
}

// Round 12
// 74.153 us; speedup vs baseline: 1.0662x; 1.0539x over previous
//
#include <hip/hip_runtime.h>
#include <math.h>

#define VOCAB   128000
#define VOCAB4  32000            // float4 per row
#define NROW    256
#define TOPC    63
#define HPR     4                // stream blocks per row
#define BS      512
#define Q4      (VOCAB4 / HPR)   // 8000 float4 per quarter
#define FIT     15
#define TAILT   (Q4 - FIT * BS)  // 320
#define LCAP    192              // per-block LDS cap (E~95, sd~10 -> +9.9 sd)
#define CAPR    (HPR * LCAP)     // 768 per-row candidate slots
#define T0      11.0f            // collect threshold; top-63 cutoff ~13.2
#define BSM     512              // merge block size

typedef float f32x4 __attribute__((ext_vector_type(4)));

// ws: [0) u32 cnt4[NROW*HPR] | [4096) f32 psum[NROW*HPR]
//     [8192) f32 cval[NROW*CAPR] | [8192+768KB) i32 cidx[NROW*CAPR]

__device__ __forceinline__ unsigned ordf(float v) {
  unsigned u = __float_as_uint(v);
  return (u & 0x80000000u) ? ~u : (u | 0x80000000u);   // order-preserving f32->u32
}

__device__ __forceinline__ void proc4(
    float4 x, int j4, float inv_t, float4* __restrict__ o4,
    float& s0, float& s1, float& s2, float& s3,
    unsigned int* nc, float* cv, int* ci)
{
  float vx = x.x*inv_t, vy = x.y*inv_t, vz = x.z*inv_t, vw = x.w*inv_t;
  f32x4 v = {vx, vy, vz, vw};
  *(f32x4*)&o4[j4] = v;
  s0 += __expf(vx); s1 += __expf(vy); s2 += __expf(vz); s3 += __expf(vw);
  // rare branch (p~0.003/elem)
  if (x.x > T0) { unsigned q = atomicAdd(nc,1u); if (q<LCAP){cv[q]=vx; ci[q]=4*j4+0;} }
  if (x.y > T0) { unsigned q = atomicAdd(nc,1u); if (q<LCAP){cv[q]=vy; ci[q]=4*j4+1;} }
  if (x.z > T0) { unsigned q = atomicAdd(nc,1u); if (q<LCAP){cv[q]=vz; ci[q]=4*j4+2;} }
  if (x.w > T0) { unsigned q = atomicAdd(nc,1u); if (q<LCAP){cv[q]=vw; ci[q]=4*j4+3;} }
}

__global__ __launch_bounds__(BS, 8) void stream_kernel(
    const float* __restrict__ logits, const float* __restrict__ temps,
    float* __restrict__ out, unsigned int* __restrict__ cnt4,
    float* __restrict__ psum, float* __restrict__ cval, int* __restrict__ cidx)
{
  const int blk = blockIdx.x;
  const int row = blk >> 2;
  const int qq  = blk & 3;
  const int tid = threadIdx.x;

  __shared__ float lcv[LCAP]; __shared__ int lci[LCAP];
  __shared__ float wsum[BS / 64];
  __shared__ unsigned int nc_sh;

  if (tid == 0) nc_sh = 0u;
  __syncthreads();

  const float temp  = temps[row];
  const float inv_t = 1.0f / ((temp == 0.0f) ? 1.0f : temp);

  const float4* __restrict__ lg4 =
      reinterpret_cast<const float4*>(logits + (size_t)row * VOCAB);
  float4* __restrict__ o4 =
      reinterpret_cast<float4*>(out + NROW + (size_t)row * VOCAB);

  float s0 = 0.f, s1 = 0.f, s2 = 0.f, s3 = 0.f;

  // ---- stream quarter-row: scale+write, sum-exp, threshold-collect ----
  int j = qq * Q4 + tid;
  #pragma unroll
  for (int g = 0; g < 7; ++g) {            // 7 pairs = 14 iters
    float4 a = lg4[j];
    float4 b = lg4[j + BS];
    proc4(a, j,      inv_t, o4, s0,s1,s2,s3, &nc_sh, lcv, lci);
    proc4(b, j + BS, inv_t, o4, s0,s1,s2,s3, &nc_sh, lcv, lci);
    j += 2 * BS;
  }
  {                                        // 15th iter
    float4 a = lg4[j];
    proc4(a, j, inv_t, o4, s0,s1,s2,s3, &nc_sh, lcv, lci);
  }
  if (tid < TAILT) {                       // tail 320 float4
    int jt = qq * Q4 + FIT * BS + tid;
    float4 a = lg4[jt];
    proc4(a, jt, inv_t, o4, s0,s1,s2,s3, &nc_sh, lcv, lci);
  }

  // ---- block sum-exp reduce -> psum (fixed order, deterministic) ----
  float s = (s0 + s1) + (s2 + s3);
  #pragma unroll
  for (int off = 32; off > 0; off >>= 1) s += __shfl_down(s, off);
  if ((tid & 63) == 0) wsum[tid >> 6] = s;
  __syncthreads();
  if (tid == 0) {
    float t = 0.f;
    #pragma unroll
    for (int w = 0; w < BS / 64; ++w) t += wsum[w];
    psum[row * HPR + qq] = t;
    cnt4[row * HPR + qq] = nc_sh;          // raw count; plain store, no atomic
  }
  __syncthreads();

  // ---- flush LDS candidates to private per-block slot (deterministic) ----
  const int nloc = ((int)nc_sh < LCAP) ? (int)nc_sh : LCAP;
  for (int i = tid; i < nloc; i += BS) {
    cval[row * CAPR + qq * LCAP + i] = lcv[i];
    cidx[row * CAPR + qq * LCAP + i] = lci[i];
  }
  // no fence, no memset: kernel boundary is the coherence point
}

__global__ __launch_bounds__(BSM) void merge_kernel(
    const float* __restrict__ logits, const float* __restrict__ temps,
    const float* __restrict__ topps, const float* __restrict__ topks,
    const float* __restrict__ noise, float* __restrict__ out,
    const unsigned int* __restrict__ cnt4, const float* __restrict__ psum,
    const float* __restrict__ cval, const int* __restrict__ cidx)
{
  const int row = blockIdx.x;
  const int tid = threadIdx.x;

  __shared__ float cv2[CAPR]; __shared__ int ci2[CAPR];
  __shared__ unsigned long long kv[CAPR];
  __shared__ float sv[64];   __shared__ int si[64];
  __shared__ float sp_s[64], sc_s[64], noi_s[64];
  __shared__ unsigned int nc2;

  if (tid < 64) noi_s[tid] = noise[(size_t)row * VOCAB + tid];

  const float temp  = temps[row];
  const float inv_t = 1.0f / ((temp == 0.0f) ? 1.0f : temp);
  const float S = (psum[row*HPR+0] + psum[row*HPR+1]) +
                  (psum[row*HPR+2] + psum[row*HPR+3]);   // fixed order

  // segment counts + compaction offsets (all threads compute identically)
  unsigned raw0 = cnt4[row*HPR+0], raw1 = cnt4[row*HPR+1];
  unsigned raw2 = cnt4[row*HPR+2], raw3 = cnt4[row*HPR+3];
  int c0 = (raw0 < LCAP) ? (int)raw0 : LCAP;
  int c1 = (raw1 < LCAP) ? (int)raw1 : LCAP;
  int c2 = (raw2 < LCAP) ? (int)raw2 : LCAP;
  int c3 = (raw3 < LCAP) ? (int)raw3 : LCAP;
  bool ovf = (raw0 > LCAP) | (raw1 > LCAP) | (raw2 > LCAP) | (raw3 > LCAP);
  int off1 = c0, off2 = c0 + c1, off3 = c0 + c1 + c2;
  int total = ovf ? (CAPR + 1) : (c0 + c1 + c2 + c3);
  int n = (total < CAPR) ? total : CAPR;

  // compact 4 private segments into contiguous LDS
  for (int i = tid; i < c0; i += BSM) {
    cv2[i] = cval[row*CAPR + 0*LCAP + i]; ci2[i] = cidx[row*CAPR + 0*LCAP + i]; }
  for (int i = tid; i < c1; i += BSM) {
    cv2[off1+i] = cval[row*CAPR + 1*LCAP + i]; ci2[off1+i] = cidx[row*CAPR + 1*LCAP + i]; }
  for (int i = tid; i < c2; i += BSM) {
    cv2[off2+i] = cval[row*CAPR + 2*LCAP + i]; ci2[off2+i] = cidx[row*CAPR + 2*LCAP + i]; }
  for (int i = tid; i < c3; i += BSM) {
    cv2[off3+i] = cval[row*CAPR + 3*LCAP + i]; ci2[off3+i] = cidx[row*CAPR + 3*LCAP + i]; }
  __syncthreads();

  // robustness ladder (dead for bench data): rescan full L3-warm row
  float thr = T0;
  for (int att = 0; att < 4 && (total < TOPC || total > CAPR); ++att) {
    thr = (total > CAPR) ? (thr + 2.0f) : (thr - 4.0f);
    __syncthreads();
    if (tid == 0) nc2 = 0u;
    __syncthreads();
    const float* __restrict__ lg = logits + (size_t)row * VOCAB;
    for (int k = tid; k < VOCAB; k += BSM) {
      float x = lg[k];
      if (x > thr) {
        unsigned p = atomicAdd(&nc2, 1u);
        if (p < CAPR) { cv2[p] = x * inv_t; ci2[p] = k; }
      }
    }
    __syncthreads();
    total = (int)nc2;
    n = (total < CAPR) ? total : CAPR;
  }

  // ---- packed sort keys: ascending u64 == (value desc, index asc) ----
  for (int i = tid; i < n; i += BSM)
    kv[i] = ((unsigned long long)(~ordf(cv2[i])) << 32) | (unsigned)ci2[i];
  __syncthreads();

  // ---- rank select: batched LDS reads ----
  for (int i = tid; i < n; i += BSM) {
    const unsigned long long me = kv[i];
    int r = 0;
    #pragma unroll 8
    for (int k = 0; k < n; ++k) r += (int)(kv[k] < me);
    if (r < 64) { sv[r] = cv2[i]; si[r] = ci2[i]; }
  }
  __syncthreads();

  const int lim = (n < TOPC) ? n : TOPC;

  // parallel per-slot prob + gumbel score
  if (tid < lim) {
    float sp = __expf(sv[tid]) * (1.0f / S);
    sp_s[tid] = sp;
    float u = noi_s[tid];
    sc_s[tid] = logf(sp) + (-logf(-logf(u)));
  }
  __syncthreads();

  // serial 63-step joint-mask scan + argmax
  if (tid == 0) {
    const float kk = topks[row];
    const float tp = topps[row];
    float cdf = 0.f, best = -INFINITY; int bestj = 0;
    for (int k = 0; k < lim; ++k) {
      if (((float)k < kk) && (cdf <= tp)) {
        float sc = sc_s[k];
        if (sc > best) { best = sc; bestj = k; }
      }
      cdf += sp_s[k];                      // exclusive cumsum semantics
    }
    int token = (n > 0) ? si[bestj] : 0;
    if (temp == 0.0f && n > 0) token = si[0];
    out[row] = (float)token;
  }
}

extern "C" void kernel_launch(void* const* d_in, const int* in_sizes, int n_in,
                              void* d_out, int out_size, void* d_ws, size_t ws_size,
                              hipStream_t stream) {
  const float* logits = (const float*)d_in[0];
  const float* temps  = (const float*)d_in[1];
  const float* topps  = (const float*)d_in[2];
  const float* topks  = (const float*)d_in[3];
  const float* noise  = (const float*)d_in[4];
  float* out = (float*)d_out;

  char* ws = (char*)d_ws;
  unsigned int* cnt4 = (unsigned int*)(ws);
  float* psum = (float*)(ws + 4096);
  float* cval = (float*)(ws + 8192);
  int*   cidx = (int*)  (ws + 8192 + (size_t)NROW * CAPR * 4);

  stream_kernel<<<NROW * HPR, BS, 0, stream>>>(logits, temps, out, cnt4, psum, cval, cidx);
  merge_kernel<<<NROW, BSM, 0, stream>>>(logits, temps, topps, topks, noise, out,
                                         cnt4, psum, cval, cidx);
}

// Round 13
// 70.215 us; speedup vs baseline: 1.1260x; 1.0561x over previous
//
#include <hip/hip_runtime.h>
#include <math.h>

#define VOCAB   128000
#define VOCAB4  32000            // float4 per row
#define NROW    256
#define TOPC    63
#define HPR     4                // stream blocks per row
#define BS      512
#define Q4      (VOCAB4 / HPR)   // 8000 float4 per quarter
#define FIT     15
#define TAILT   (Q4 - FIT * BS)  // 320
#define LCAP    192              // per-block LDS cap (E~95, sd~10 -> +9.9 sd)
#define CAPR    (HPR * LCAP)     // 768 per-row candidate slots
#define T0      11.0f            // collect threshold; top-63 cutoff ~13.2
#define BSM     512              // merge block size

typedef float f32x4 __attribute__((ext_vector_type(4)));

// ws: [0) u32 cnt4[NROW*HPR] | [4096) f32 psum[NROW*HPR]
//     [8192) f32 cval[NROW*CAPR] | [8192+768KB) i32 cidx[NROW*CAPR]

__device__ __forceinline__ unsigned ordf(float v) {
  unsigned u = __float_as_uint(v);
  return (u & 0x80000000u) ? ~u : (u | 0x80000000u);   // order-preserving f32->u32
}

__device__ __forceinline__ void proc4(
    float4 x, int j4, float inv_t, float4* __restrict__ o4,
    float& s0, float& s1, float& s2, float& s3,
    unsigned int* nc, float* cv, int* ci)
{
  float vx = x.x*inv_t, vy = x.y*inv_t, vz = x.z*inv_t, vw = x.w*inv_t;
  f32x4 v = {vx, vy, vz, vw};
  // SINGLE CHANGE vs R12: nontemporal store — out is write-once/never-read;
  // keep it out of L3 so logits stay fully L3-resident across graph replays.
  __builtin_nontemporal_store(v, (f32x4*)&o4[j4]);
  s0 += __expf(vx); s1 += __expf(vy); s2 += __expf(vz); s3 += __expf(vw);
  // rare branch (p~0.003/elem)
  if (x.x > T0) { unsigned q = atomicAdd(nc,1u); if (q<LCAP){cv[q]=vx; ci[q]=4*j4+0;} }
  if (x.y > T0) { unsigned q = atomicAdd(nc,1u); if (q<LCAP){cv[q]=vy; ci[q]=4*j4+1;} }
  if (x.z > T0) { unsigned q = atomicAdd(nc,1u); if (q<LCAP){cv[q]=vz; ci[q]=4*j4+2;} }
  if (x.w > T0) { unsigned q = atomicAdd(nc,1u); if (q<LCAP){cv[q]=vw; ci[q]=4*j4+3;} }
}

__global__ __launch_bounds__(BS, 8) void stream_kernel(
    const float* __restrict__ logits, const float* __restrict__ temps,
    float* __restrict__ out, unsigned int* __restrict__ cnt4,
    float* __restrict__ psum, float* __restrict__ cval, int* __restrict__ cidx)
{
  const int blk = blockIdx.x;
  const int row = blk >> 2;
  const int qq  = blk & 3;
  const int tid = threadIdx.x;

  __shared__ float lcv[LCAP]; __shared__ int lci[LCAP];
  __shared__ float wsum[BS / 64];
  __shared__ unsigned int nc_sh;

  if (tid == 0) nc_sh = 0u;
  __syncthreads();

  const float temp  = temps[row];
  const float inv_t = 1.0f / ((temp == 0.0f) ? 1.0f : temp);

  const float4* __restrict__ lg4 =
      reinterpret_cast<const float4*>(logits + (size_t)row * VOCAB);
  float4* __restrict__ o4 =
      reinterpret_cast<float4*>(out + NROW + (size_t)row * VOCAB);

  float s0 = 0.f, s1 = 0.f, s2 = 0.f, s3 = 0.f;

  // ---- stream quarter-row: scale+write, sum-exp, threshold-collect ----
  int j = qq * Q4 + tid;
  #pragma unroll
  for (int g = 0; g < 7; ++g) {            // 7 pairs = 14 iters
    float4 a = lg4[j];
    float4 b = lg4[j + BS];
    proc4(a, j,      inv_t, o4, s0,s1,s2,s3, &nc_sh, lcv, lci);
    proc4(b, j + BS, inv_t, o4, s0,s1,s2,s3, &nc_sh, lcv, lci);
    j += 2 * BS;
  }
  {                                        // 15th iter
    float4 a = lg4[j];
    proc4(a, j, inv_t, o4, s0,s1,s2,s3, &nc_sh, lcv, lci);
  }
  if (tid < TAILT) {                       // tail 320 float4
    int jt = qq * Q4 + FIT * BS + tid;
    float4 a = lg4[jt];
    proc4(a, jt, inv_t, o4, s0,s1,s2,s3, &nc_sh, lcv, lci);
  }

  // ---- block sum-exp reduce -> psum (fixed order, deterministic) ----
  float s = (s0 + s1) + (s2 + s3);
  #pragma unroll
  for (int off = 32; off > 0; off >>= 1) s += __shfl_down(s, off);
  if ((tid & 63) == 0) wsum[tid >> 6] = s;
  __syncthreads();
  if (tid == 0) {
    float t = 0.f;
    #pragma unroll
    for (int w = 0; w < BS / 64; ++w) t += wsum[w];
    psum[row * HPR + qq] = t;
    cnt4[row * HPR + qq] = nc_sh;          // raw count; plain store, no atomic
  }
  __syncthreads();

  // ---- flush LDS candidates to private per-block slot (deterministic) ----
  const int nloc = ((int)nc_sh < LCAP) ? (int)nc_sh : LCAP;
  for (int i = tid; i < nloc; i += BS) {
    cval[row * CAPR + qq * LCAP + i] = lcv[i];
    cidx[row * CAPR + qq * LCAP + i] = lci[i];
  }
  // no fence, no memset: kernel boundary is the coherence point
}

__global__ __launch_bounds__(BSM) void merge_kernel(
    const float* __restrict__ logits, const float* __restrict__ temps,
    const float* __restrict__ topps, const float* __restrict__ topks,
    const float* __restrict__ noise, float* __restrict__ out,
    const unsigned int* __restrict__ cnt4, const float* __restrict__ psum,
    const float* __restrict__ cval, const int* __restrict__ cidx)
{
  const int row = blockIdx.x;
  const int tid = threadIdx.x;

  __shared__ float cv2[CAPR]; __shared__ int ci2[CAPR];
  __shared__ unsigned long long kv[CAPR];
  __shared__ float sv[64];   __shared__ int si[64];
  __shared__ float sp_s[64], sc_s[64], noi_s[64];
  __shared__ unsigned int nc2;

  if (tid < 64) noi_s[tid] = noise[(size_t)row * VOCAB + tid];

  const float temp  = temps[row];
  const float inv_t = 1.0f / ((temp == 0.0f) ? 1.0f : temp);
  const float S = (psum[row*HPR+0] + psum[row*HPR+1]) +
                  (psum[row*HPR+2] + psum[row*HPR+3]);   // fixed order

  // segment counts + compaction offsets (all threads compute identically)
  unsigned raw0 = cnt4[row*HPR+0], raw1 = cnt4[row*HPR+1];
  unsigned raw2 = cnt4[row*HPR+2], raw3 = cnt4[row*HPR+3];
  int c0 = (raw0 < LCAP) ? (int)raw0 : LCAP;
  int c1 = (raw1 < LCAP) ? (int)raw1 : LCAP;
  int c2 = (raw2 < LCAP) ? (int)raw2 : LCAP;
  int c3 = (raw3 < LCAP) ? (int)raw3 : LCAP;
  bool ovf = (raw0 > LCAP) | (raw1 > LCAP) | (raw2 > LCAP) | (raw3 > LCAP);
  int off1 = c0, off2 = c0 + c1, off3 = c0 + c1 + c2;
  int total = ovf ? (CAPR + 1) : (c0 + c1 + c2 + c3);
  int n = (total < CAPR) ? total : CAPR;

  // compact 4 private segments into contiguous LDS
  for (int i = tid; i < c0; i += BSM) {
    cv2[i] = cval[row*CAPR + 0*LCAP + i]; ci2[i] = cidx[row*CAPR + 0*LCAP + i]; }
  for (int i = tid; i < c1; i += BSM) {
    cv2[off1+i] = cval[row*CAPR + 1*LCAP + i]; ci2[off1+i] = cidx[row*CAPR + 1*LCAP + i]; }
  for (int i = tid; i < c2; i += BSM) {
    cv2[off2+i] = cval[row*CAPR + 2*LCAP + i]; ci2[off2+i] = cidx[row*CAPR + 2*LCAP + i]; }
  for (int i = tid; i < c3; i += BSM) {
    cv2[off3+i] = cval[row*CAPR + 3*LCAP + i]; ci2[off3+i] = cidx[row*CAPR + 3*LCAP + i]; }
  __syncthreads();

  // robustness ladder (dead for bench data): rescan full L3-warm row
  float thr = T0;
  for (int att = 0; att < 4 && (total < TOPC || total > CAPR); ++att) {
    thr = (total > CAPR) ? (thr + 2.0f) : (thr - 4.0f);
    __syncthreads();
    if (tid == 0) nc2 = 0u;
    __syncthreads();
    const float* __restrict__ lg = logits + (size_t)row * VOCAB;
    for (int k = tid; k < VOCAB; k += BSM) {
      float x = lg[k];
      if (x > thr) {
        unsigned p = atomicAdd(&nc2, 1u);
        if (p < CAPR) { cv2[p] = x * inv_t; ci2[p] = k; }
      }
    }
    __syncthreads();
    total = (int)nc2;
    n = (total < CAPR) ? total : CAPR;
  }

  // ---- packed sort keys: ascending u64 == (value desc, index asc) ----
  for (int i = tid; i < n; i += BSM)
    kv[i] = ((unsigned long long)(~ordf(cv2[i])) << 32) | (unsigned)ci2[i];
  __syncthreads();

  // ---- rank select: batched LDS reads ----
  for (int i = tid; i < n; i += BSM) {
    const unsigned long long me = kv[i];
    int r = 0;
    #pragma unroll 8
    for (int k = 0; k < n; ++k) r += (int)(kv[k] < me);
    if (r < 64) { sv[r] = cv2[i]; si[r] = ci2[i]; }
  }
  __syncthreads();

  const int lim = (n < TOPC) ? n : TOPC;

  // parallel per-slot prob + gumbel score
  if (tid < lim) {
    float sp = __expf(sv[tid]) * (1.0f / S);
    sp_s[tid] = sp;
    float u = noi_s[tid];
    sc_s[tid] = logf(sp) + (-logf(-logf(u)));
  }
  __syncthreads();

  // serial 63-step joint-mask scan + argmax
  if (tid == 0) {
    const float kk = topks[row];
    const float tp = topps[row];
    float cdf = 0.f, best = -INFINITY; int bestj = 0;
    for (int k = 0; k < lim; ++k) {
      if (((float)k < kk) && (cdf <= tp)) {
        float sc = sc_s[k];
        if (sc > best) { best = sc; bestj = k; }
      }
      cdf += sp_s[k];                      // exclusive cumsum semantics
    }
    int token = (n > 0) ? si[bestj] : 0;
    if (temp == 0.0f && n > 0) token = si[0];
    out[row] = (float)token;
  }
}

extern "C" void kernel_launch(void* const* d_in, const int* in_sizes, int n_in,
                              void* d_out, int out_size, void* d_ws, size_t ws_size,
                              hipStream_t stream) {
  const float* logits = (const float*)d_in[0];
  const float* temps  = (const float*)d_in[1];
  const float* topps  = (const float*)d_in[2];
  const float* topks  = (const float*)d_in[3];
  const float* noise  = (const float*)d_in[4];
  float* out = (float*)d_out;

  char* ws = (char*)d_ws;
  unsigned int* cnt4 = (unsigned int*)(ws);
  float* psum = (float*)(ws + 4096);
  float* cval = (float*)(ws + 8192);
  int*   cidx = (int*)  (ws + 8192 + (size_t)NROW * CAPR * 4);

  stream_kernel<<<NROW * HPR, BS, 0, stream>>>(logits, temps, out, cnt4, psum, cval, cidx);
  merge_kernel<<<NROW, BSM, 0, stream>>>(logits, temps, topps, topks, noise, out,
                                         cnt4, psum, cval, cidx);
}

// Round 14
// 70.108 us; speedup vs baseline: 1.1277x; 1.0015x over previous
//
#include <hip/hip_runtime.h>
#include <math.h>

#define VOCAB   128000
#define VOCAB4  32000            // float4 per row
#define NROW    256
#define TOPC    63
#define HPR     8                // stream blocks per row
#define BS      256
#define Q4      (VOCAB4 / HPR)   // 4000 float4 per chunk
#define FIT     15
#define TAILT   (Q4 - FIT * BS)  // 160
#define LCAP    128              // per-block LDS cap (E~48, sd~7 -> +11 sd)
#define CAPR    (HPR * LCAP)     // 1024 per-row candidate slots
#define T0      11.0f            // collect threshold; top-63 cutoff ~13.2
#define BSM     512              // merge block size

typedef float f32x4 __attribute__((ext_vector_type(4)));

// ws: [0) u32 cnt4[NROW*HPR] (8KB) | [8192) f32 psum[NROW*HPR] (8KB)
//     [16384) f32 cval[NROW*CAPR] (1MB) | [+1MB) i32 cidx[NROW*CAPR] (1MB)

__device__ __forceinline__ unsigned ordf(float v) {
  unsigned u = __float_as_uint(v);
  return (u & 0x80000000u) ? ~u : (u | 0x80000000u);   // order-preserving f32->u32
}

// write-through + non-temporal: full-line streaming store, no MALL allocation
#define GSTNT(ptr, val) \
  asm volatile("global_store_dwordx4 %0, %1, off sc1 nt" \
               :: "v"(ptr), "v"(val) : "memory")

__device__ __forceinline__ void proc4(
    float4 x, int j4, float inv_t, float* __restrict__ outp,
    float& s0, float& s1, float& s2, float& s3,
    unsigned int* nc, float* cv, int* ci)
{
  float vx = x.x*inv_t, vy = x.y*inv_t, vz = x.z*inv_t, vw = x.w*inv_t;
  f32x4 v = {vx, vy, vz, vw};
  GSTNT(outp + 4*(size_t)j4, v);
  s0 += __expf(vx); s1 += __expf(vy); s2 += __expf(vz); s3 += __expf(vw);
  // rare branch (p~0.003/elem)
  if (x.x > T0) { unsigned q = atomicAdd(nc,1u); if (q<LCAP){cv[q]=vx; ci[q]=4*j4+0;} }
  if (x.y > T0) { unsigned q = atomicAdd(nc,1u); if (q<LCAP){cv[q]=vy; ci[q]=4*j4+1;} }
  if (x.z > T0) { unsigned q = atomicAdd(nc,1u); if (q<LCAP){cv[q]=vz; ci[q]=4*j4+2;} }
  if (x.w > T0) { unsigned q = atomicAdd(nc,1u); if (q<LCAP){cv[q]=vw; ci[q]=4*j4+3;} }
}

__global__ __launch_bounds__(BS, 8) void stream_kernel(
    const float* __restrict__ logits, const float* __restrict__ temps,
    float* __restrict__ out, unsigned int* __restrict__ cnt4,
    float* __restrict__ psum, float* __restrict__ cval, int* __restrict__ cidx)
{
  const int blk = blockIdx.x;
  const int row = blk >> 3;
  const int qq  = blk & 7;
  const int tid = threadIdx.x;

  __shared__ float lcv[LCAP]; __shared__ int lci[LCAP];
  __shared__ float wsum[BS / 64];
  __shared__ unsigned int nc_sh;

  if (tid == 0) nc_sh = 0u;
  __syncthreads();

  const float temp  = temps[row];
  const float inv_t = 1.0f / ((temp == 0.0f) ? 1.0f : temp);

  const float4* __restrict__ lg4 =
      reinterpret_cast<const float4*>(logits + (size_t)row * VOCAB);
  float* __restrict__ outp = out + NROW + (size_t)row * VOCAB;

  float s0 = 0.f, s1 = 0.f, s2 = 0.f, s3 = 0.f;

  // ---- stream chunk: scale+write, sum-exp, threshold-collect ----
  int j = qq * Q4 + tid;
  #pragma unroll
  for (int g = 0; g < 7; ++g) {            // 7 pairs = 14 iters
    float4 a = lg4[j];
    float4 b = lg4[j + BS];
    proc4(a, j,      inv_t, outp, s0,s1,s2,s3, &nc_sh, lcv, lci);
    proc4(b, j + BS, inv_t, outp, s0,s1,s2,s3, &nc_sh, lcv, lci);
    j += 2 * BS;
  }
  {                                        // 15th iter
    float4 a = lg4[j];
    proc4(a, j, inv_t, outp, s0,s1,s2,s3, &nc_sh, lcv, lci);
  }
  if (tid < TAILT) {                       // tail 160 float4
    int jt = qq * Q4 + FIT * BS + tid;
    float4 a = lg4[jt];
    proc4(a, jt, inv_t, outp, s0,s1,s2,s3, &nc_sh, lcv, lci);
  }

  // ---- block sum-exp reduce -> psum (fixed order, deterministic) ----
  float s = (s0 + s1) + (s2 + s3);
  #pragma unroll
  for (int off = 32; off > 0; off >>= 1) s += __shfl_down(s, off);
  if ((tid & 63) == 0) wsum[tid >> 6] = s;
  __syncthreads();
  if (tid == 0) {
    float t = 0.f;
    #pragma unroll
    for (int w = 0; w < BS / 64; ++w) t += wsum[w];
    psum[row * HPR + qq] = t;
    cnt4[row * HPR + qq] = nc_sh;          // raw count; plain store, no atomic
  }
  __syncthreads();

  // ---- flush LDS candidates to private per-block slot (deterministic) ----
  const int nloc = ((int)nc_sh < LCAP) ? (int)nc_sh : LCAP;
  for (int i = tid; i < nloc; i += BS) {
    cval[row * CAPR + qq * LCAP + i] = lcv[i];
    cidx[row * CAPR + qq * LCAP + i] = lci[i];
  }
  // no fence, no memset: kernel boundary is the coherence point
}

__global__ __launch_bounds__(BSM) void merge_kernel(
    const float* __restrict__ logits, const float* __restrict__ temps,
    const float* __restrict__ topps, const float* __restrict__ topks,
    const float* __restrict__ noise, float* __restrict__ out,
    const unsigned int* __restrict__ cnt4, const float* __restrict__ psum,
    const float* __restrict__ cval, const int* __restrict__ cidx)
{
  const int row = blockIdx.x;
  const int tid = threadIdx.x;

  __shared__ float cv2[CAPR]; __shared__ int ci2[CAPR];
  __shared__ unsigned long long kv[CAPR];
  __shared__ float sv[64];   __shared__ int si[64];
  __shared__ float sp_s[64], sc_s[64], noi_s[64];
  __shared__ unsigned int nc2;

  if (tid < 64) noi_s[tid] = noise[(size_t)row * VOCAB + tid];

  const float temp  = temps[row];
  const float inv_t = 1.0f / ((temp == 0.0f) ? 1.0f : temp);

  // fixed-order sum of HPR partials: deterministic
  float S = 0.f;
  #pragma unroll
  for (int s2 = 0; s2 < HPR; ++s2) S += psum[row * HPR + s2];

  // segment counts + compaction offsets (all threads compute identically)
  int c[HPR], off[HPR]; bool ovf = false; int tot = 0;
  #pragma unroll
  for (int s2 = 0; s2 < HPR; ++s2) {
    unsigned raw = cnt4[row * HPR + s2];
    int cc = (raw < (unsigned)LCAP) ? (int)raw : LCAP;
    ovf |= (raw > (unsigned)LCAP);
    c[s2] = cc; off[s2] = tot; tot += cc;
  }
  int total = ovf ? (CAPR + 1) : tot;
  int n = (total < CAPR) ? total : CAPR;

  // compact HPR private segments into contiguous LDS
  #pragma unroll
  for (int s2 = 0; s2 < HPR; ++s2)
    for (int i = tid; i < c[s2]; i += BSM) {
      cv2[off[s2] + i] = cval[row * CAPR + s2 * LCAP + i];
      ci2[off[s2] + i] = cidx[row * CAPR + s2 * LCAP + i];
    }
  __syncthreads();

  // robustness ladder (dead for bench data): rescan full L3-warm row
  float thr = T0;
  for (int att = 0; att < 4 && (total < TOPC || total > CAPR); ++att) {
    thr = (total > CAPR) ? (thr + 2.0f) : (thr - 4.0f);
    __syncthreads();
    if (tid == 0) nc2 = 0u;
    __syncthreads();
    const float* __restrict__ lg = logits + (size_t)row * VOCAB;
    for (int k = tid; k < VOCAB; k += BSM) {
      float x = lg[k];
      if (x > thr) {
        unsigned p = atomicAdd(&nc2, 1u);
        if (p < CAPR) { cv2[p] = x * inv_t; ci2[p] = k; }
      }
    }
    __syncthreads();
    total = (int)nc2;
    n = (total < CAPR) ? total : CAPR;
  }

  // ---- packed sort keys: ascending u64 == (value desc, index asc) ----
  for (int i = tid; i < n; i += BSM)
    kv[i] = ((unsigned long long)(~ordf(cv2[i])) << 32) | (unsigned)ci2[i];
  __syncthreads();

  // ---- rank select: batched LDS reads ----
  for (int i = tid; i < n; i += BSM) {
    const unsigned long long me = kv[i];
    int r = 0;
    #pragma unroll 8
    for (int k = 0; k < n; ++k) r += (int)(kv[k] < me);
    if (r < 64) { sv[r] = cv2[i]; si[r] = ci2[i]; }
  }
  __syncthreads();

  const int lim = (n < TOPC) ? n : TOPC;

  // parallel per-slot prob + gumbel score
  if (tid < lim) {
    float sp = __expf(sv[tid]) * (1.0f / S);
    sp_s[tid] = sp;
    float u = noi_s[tid];
    sc_s[tid] = logf(sp) + (-logf(-logf(u)));
  }
  __syncthreads();

  // serial 63-step joint-mask scan + argmax
  if (tid == 0) {
    const float kk = topks[row];
    const float tp = topps[row];
    float cdf = 0.f, best = -INFINITY; int bestj = 0;
    for (int k = 0; k < lim; ++k) {
      if (((float)k < kk) && (cdf <= tp)) {
        float sc = sc_s[k];
        if (sc > best) { best = sc; bestj = k; }
      }
      cdf += sp_s[k];                      // exclusive cumsum semantics
    }
    int token = (n > 0) ? si[bestj] : 0;
    if (temp == 0.0f && n > 0) token = si[0];
    out[row] = (float)token;
  }
}

extern "C" void kernel_launch(void* const* d_in, const int* in_sizes, int n_in,
                              void* d_out, int out_size, void* d_ws, size_t ws_size,
                              hipStream_t stream) {
  const float* logits = (const float*)d_in[0];
  const float* temps  = (const float*)d_in[1];
  const float* topps  = (const float*)d_in[2];
  const float* topks  = (const float*)d_in[3];
  const float* noise  = (const float*)d_in[4];
  float* out = (float*)d_out;

  char* ws = (char*)d_ws;
  unsigned int* cnt4 = (unsigned int*)(ws);
  float* psum = (float*)(ws + 8192);
  float* cval = (float*)(ws + 16384);
  int*   cidx = (int*)  (ws + 16384 + (size_t)NROW * CAPR * 4);

  stream_kernel<<<NROW * HPR, BS, 0, stream>>>(logits, temps, out, cnt4, psum, cval, cidx);
  merge_kernel<<<NROW, BSM, 0, stream>>>(logits, temps, topps, topks, noise, out,
                                         cnt4, psum, cval, cidx);
}